// Round 15
// baseline (80.637 us; speedup 1.0000x reference)
//
#include <hip/hip_runtime.h>
#include <hip/hip_fp16.h>

#define BATCH 128
#define NC1   1152
#define ND1   8
#define NC2   10
#define ND2   16
#define SDIM  (NC2 * ND2)    // 160

// kernel B tiling
#define CB 16                // caps per block
#define BB 32                // batch per block (two halves of 16, parallel threads)

__device__ __forceinline__ unsigned pack_h2(float a, float b) {
    __half2 h = __floats2half2_rn(a, b);
    return *reinterpret_cast<unsigned*>(&h);
}
__device__ __forceinline__ float2 unpack_h2(unsigned v) {
    __half2 h = *reinterpret_cast<__half2*>(&v);
    return __half22float2(h);
}
__device__ __forceinline__ unsigned pmul_h2(unsigned a, unsigned b) {
    __half2 ha = *reinterpret_cast<__half2*>(&a);
    __half2 hb = *reinterpret_cast<__half2*>(&b);
    __half2 r = __hmul2(ha, hb);
    return *reinterpret_cast<unsigned*>(&r);
}
__device__ __forceinline__ unsigned padd_h2(unsigned a, unsigned b) {
    __half2 ha = *reinterpret_cast<__half2*>(&a);
    __half2 hb = *reinterpret_cast<__half2*>(&b);
    __half2 r = __hadd2(ha, hb);
    return *reinterpret_cast<unsigned*>(&r);
}

// DPP row-rotate (within 16-lane row) on the VALU pipe.
template<int CTRL>
__device__ __forceinline__ unsigned dpp_mov(unsigned v) {
    return (unsigned)__builtin_amdgcn_mov_dpp((int)v, CTRL, 0xF, 0xF, true);
}
__device__ __forceinline__ unsigned row_reduce_h2(unsigned t2) {
    t2 = padd_h2(t2, dpp_mov<0x128>(t2));   // ror 8
    t2 = padd_h2(t2, dpp_mov<0x124>(t2));   // ror 4
    t2 = padd_h2(t2, dpp_mov<0x122>(t2));   // ror 2
    t2 = padd_h2(t2, dpp_mov<0x121>(t2));   // ror 1
    return t2;
}

// ---- zero the s0 accumulator (atomics target) --------------------------
__global__ void caps_zero(float* __restrict__ s0) {
    s0[blockIdx.x * 256 + threadIdx.x] = 0.0f;   // grid 80 x 256 = 20480
}

// ---- Kernel B: u_hat (f16x2 -> ws) + fold pass-0 sum via atomics --------
// Round-9 per-thread structure EXACTLY (80-reg f32 W, 5-store jp loop,
// wave shfl + atomics), but 512 threads: two batch-halves run in PARALLEL
// threads (bh = tid>>8) instead of sequentially -> 8 waves/block at
// 1 block/CU = 2 waves/SIMD (was 1), doubling latency overlap. Live set
// ~110 VGPR fits the 128 cap of 512-thread blocks (R13 datum).
__global__ __launch_bounds__(512, 1) void caps_uhat(
    const float* __restrict__ x,     // [B, C1*D1]
    const float* __restrict__ W,     // [C1, C2, D2, D1]
    unsigned* __restrict__ u_ws,     // [B][5][C1][16]
    float* __restrict__ s0)          // [B][SDIM] (pre-zeroed)
{
    const int cb  = blockIdx.x;      // 0..71
    const int bb  = blockIdx.y;      // 0..3
    const int tid = threadIdx.x;
    const int bh  = tid >> 8;        // 0/1: batch half
    const int cl  = (tid >> 4) & 15; // 0..15 local capsule
    const int d   = tid & 15;
    const int wl  = tid & 63;        // lane in wave

    __shared__ float prim[BB][CB][ND1];  // 16 KB

    for (int i = tid; i < BB * CB; i += 512) {
        const int b = i >> 4, c = i & 15;
        const float* xr = x + ((size_t)(bb * BB + b) * NC1 + (cb * CB + c)) * ND1;
        float4 a0 = *(const float4*)(xr);
        float4 a1 = *(const float4*)(xr + 4);
        float sq = a0.x*a0.x + a0.y*a0.y + a0.z*a0.z + a0.w*a0.w
                 + a1.x*a1.x + a1.y*a1.y + a1.z*a1.z + a1.w*a1.w;
        float g = (sq / (1.0f + sq)) * rsqrtf(sq + 1e-8f);
        prim[b][c][0] = a0.x * g; prim[b][c][1] = a0.y * g;
        prim[b][c][2] = a0.z * g; prim[b][c][3] = a0.w * g;
        prim[b][c][4] = a1.x * g; prim[b][c][5] = a1.y * g;
        prim[b][c][6] = a1.z * g; prim[b][c][7] = a1.w * g;
    }
    __syncthreads();

    const int c_glob = cb * CB + cl;
    float w[NC2][ND1];               // 80 VGPRs f32 (round-9 exact)
    #pragma unroll
    for (int j = 0; j < NC2; ++j) {
        const float* Wr = W + (((size_t)c_glob * NC2 + j) * ND2 + d) * ND1;
        float4 w0 = *(const float4*)(Wr);
        float4 w1 = *(const float4*)(Wr + 4);
        w[j][0] = w0.x; w[j][1] = w0.y; w[j][2] = w0.z; w[j][3] = w0.w;
        w[j][4] = w1.x; w[j][5] = w1.y; w[j][6] = w1.z; w[j][7] = w1.w;
    }

    for (int k = 0; k < 16; ++k) {   // 16 iters: this half's batch elems
        const int b = bh * 16 + ((k + cb) & 15);   // stagger within half
        const int bglob = bb * BB + b;
        float p[ND1];
        #pragma unroll
        for (int kk = 0; kk < ND1; ++kk) p[kk] = prim[b][cl][kk];

        unsigned* ur = u_ws + ((size_t)bglob * 5 * NC1 + c_glob) * 16 + d;
        #pragma unroll
        for (int jp = 0; jp < 5; ++jp) {
            float u0 = 0.f, u1 = 0.f;
            #pragma unroll
            for (int kk = 0; kk < ND1; ++kk) {
                u0 += w[2*jp  ][kk] * p[kk];
                u1 += w[2*jp+1][kk] * p[kk];
            }
            unsigned pk = pack_h2(u0, u1);
            ur[(size_t)jp * (NC1 * 16)] = pk;
            // pass-0 partial: packed shfl over the wave's 4 caps (xor16,32)
            pk = padd_h2(pk, (unsigned)__shfl_xor((int)pk, 16));
            pk = padd_h2(pk, (unsigned)__shfl_xor((int)pk, 32));
            if (wl < 16) {
                float2 f = unpack_h2(pk);
                atomicAdd(&s0[(size_t)bglob * SDIM + (2*jp)   * 16 + d], f.x);
                atomicAdd(&s0[(size_t)bglob * SDIM + (2*jp+1) * 16 + d], f.y);
            }
        }
    }
}

// ---- one routing pass: partial s per (b, quarter) -- ROUND-9 EXACT ------
__global__ __launch_bounds__(512, 1) void caps_pass(
    const unsigned* __restrict__ u_ws,  // [B][5][C1][16] f16x2
    const float* __restrict__ sv,       // mode0: s0 [B][SDIM]; mode1: v [B][SDIM]
    const float* __restrict__ bias,     // [SDIM]
    float* __restrict__ spart,          // [B][4][SDIM]
    int mode)
{
    const int bx   = blockIdx.x;
    const int b    = bx >> 2;
    const int q    = bx & 3;
    const int tid  = threadIdx.x;
    const int grp  = tid >> 4;   // 0..31
    const int d    = tid & 15;
    const int wave = tid >> 6;   // 0..7

    __shared__ float vl[SDIM];
    __shared__ float sred[8][SDIM];

    if (tid < SDIM) {
        float s = sv[(size_t)b * SDIM + tid];
        if (mode == 0) {
            s = 0.1f * s + bias[tid];
            float sq = s * s;
            sq += __shfl_xor(sq, 1); sq += __shfl_xor(sq, 2);
            sq += __shfl_xor(sq, 4); sq += __shfl_xor(sq, 8);
            s = (sq / (1.0f + sq)) * rsqrtf(sq + 1e-8f) * s;
        }
        vl[tid] = s;
    }
    __syncthreads();

    unsigned vsf[5];
    #pragma unroll
    for (int jp = 0; jp < 5; ++jp)
        vsf[jp] = pack_h2(vl[(2*jp)*16 + d], vl[(2*jp+1)*16 + d]);

    const unsigned* ub = u_ws + (size_t)b * 5 * NC1 * 16 + d;
    const int c0 = q * 288 + grp;       // caps c0 + i*32, i < 9

    float sp[NC2];
    #pragma unroll
    for (int j = 0; j < NC2; ++j) sp[j] = 0.0f;

    unsigned o[5], on[5];
    #pragma unroll
    for (int jp = 0; jp < 5; ++jp)
        o[jp] = ub[(size_t)jp * (NC1 * 16) + (size_t)c0 * 16];

    for (int i = 0; i < 9; ++i) {
        if (i + 1 < 9) {
            const int c = c0 + (i + 1) * 32;
            #pragma unroll
            for (int jp = 0; jp < 5; ++jp)
                on[jp] = ub[(size_t)jp * (NC1 * 16) + (size_t)c * 16];
        }
        float u[NC2], r[NC2];
        #pragma unroll
        for (int jp = 0; jp < 5; ++jp) {
            float2 f = unpack_h2(o[jp]);
            u[2*jp] = f.x; u[2*jp+1] = f.y;
            unsigned t2 = row_reduce_h2(pmul_h2(o[jp], vsf[jp]));  // VALU-only
            float2 rr = unpack_h2(t2);
            r[2*jp] = rr.x; r[2*jp+1] = rr.y;
        }
        float ssum = 0.0f;
        #pragma unroll
        for (int j = 0; j < NC2; ++j) { r[j] = __expf(r[j]); ssum += r[j]; }
        float inv = 1.0f / ssum;
        #pragma unroll
        for (int j = 0; j < NC2; ++j) sp[j] += (r[j] * inv) * u[j];
        #pragma unroll
        for (int jp = 0; jp < 5; ++jp) o[jp] = on[jp];
    }

    #pragma unroll
    for (int j = 0; j < NC2; ++j) {
        sp[j] += __shfl_xor(sp[j], 16);
        sp[j] += __shfl_xor(sp[j], 32);
    }
    if ((tid & 63) < 16) {
        #pragma unroll
        for (int j = 0; j < NC2; ++j) sred[wave][j * 16 + d] = sp[j];
    }
    __syncthreads();
    if (tid < SDIM) {
        float acc = 0.0f;
        #pragma unroll
        for (int w = 0; w < 8; ++w) acc += sred[w][tid];
        spart[((size_t)b * 4 + q) * SDIM + tid] = acc;
    }
}

// ---- combine: v = squash(0.1*s0+bias) + squash(sum spart + bias) ---------
__global__ void caps_comb1(const float* __restrict__ s0,
                           const float* __restrict__ spart,
                           const float* __restrict__ bias,
                           float* __restrict__ v) {   // grid 128 x 192
    const int b = blockIdx.x, tid = threadIdx.x;
    if (tid >= SDIM) return;
    float bv = bias[tid];
    float s_a = 0.1f * s0[(size_t)b * SDIM + tid] + bv;
    float s_b = spart[((size_t)b * 4 + 0) * SDIM + tid]
              + spart[((size_t)b * 4 + 1) * SDIM + tid]
              + spart[((size_t)b * 4 + 2) * SDIM + tid]
              + spart[((size_t)b * 4 + 3) * SDIM + tid] + bv;
    float qa = s_a * s_a;
    qa += __shfl_xor(qa, 1); qa += __shfl_xor(qa, 2);
    qa += __shfl_xor(qa, 4); qa += __shfl_xor(qa, 8);
    float qb = s_b * s_b;
    qb += __shfl_xor(qb, 1); qb += __shfl_xor(qb, 2);
    qb += __shfl_xor(qb, 4); qb += __shfl_xor(qb, 8);
    float v0 = (qa / (1.0f + qa)) * rsqrtf(qa + 1e-8f) * s_a;
    float v1 = (qb / (1.0f + qb)) * rsqrtf(qb + 1e-8f) * s_b;
    v[(size_t)b * SDIM + tid] = v0 + v1;
}

// ---- combine quarters -> out = squash(s)  (final) ------------------------
__global__ void caps_comb2(const float* __restrict__ spart,
                           const float* __restrict__ bias,
                           float* __restrict__ out) { // grid 128 x 192
    const int b = blockIdx.x, tid = threadIdx.x;
    if (tid >= SDIM) return;
    float s = spart[((size_t)b * 4 + 0) * SDIM + tid]
            + spart[((size_t)b * 4 + 1) * SDIM + tid]
            + spart[((size_t)b * 4 + 2) * SDIM + tid]
            + spart[((size_t)b * 4 + 3) * SDIM + tid] + bias[tid];
    float sq = s * s;
    sq += __shfl_xor(sq, 1); sq += __shfl_xor(sq, 2);
    sq += __shfl_xor(sq, 4); sq += __shfl_xor(sq, 8);
    out[(size_t)b * SDIM + tid] = (sq / (1.0f + sq)) * rsqrtf(sq + 1e-8f) * s;
}

// ---- Fallback: round-1 fused kernel (proven, 198 us) ---------------------
__global__ __launch_bounds__(1024) void caps_fused(
    const float* __restrict__ x, const float* __restrict__ W,
    const float* __restrict__ bias, float* __restrict__ out)
{
    const int b    = blockIdx.x;
    const int tid  = threadIdx.x;
    const int grp  = tid >> 4;
    const int d    = tid & 15;
    const int wave = tid >> 6;
    const int lane = tid & 63;

    __shared__ float prim[NC1][ND1];
    __shared__ float sred[16][SDIM];
    __shared__ float vbuf[SDIM];

    const float* xb = x + (size_t)b * (NC1 * ND1);
    for (int c = tid; c < NC1; c += 1024) {
        float4 a0 = *(const float4*)(xb + c * 8);
        float4 a1 = *(const float4*)(xb + c * 8 + 4);
        float sq = a0.x*a0.x + a0.y*a0.y + a0.z*a0.z + a0.w*a0.w
                 + a1.x*a1.x + a1.y*a1.y + a1.z*a1.z + a1.w*a1.w;
        float g = (sq / (1.0f + sq)) * rsqrtf(sq + 1e-8f);
        prim[c][0] = a0.x * g; prim[c][1] = a0.y * g;
        prim[c][2] = a0.z * g; prim[c][3] = a0.w * g;
        prim[c][4] = a1.x * g; prim[c][5] = a1.y * g;
        prim[c][6] = a1.z * g; prim[c][7] = a1.w * g;
    }
    __syncthreads();

    float vsum[NC2], sp[NC2];
    for (int pass = 0; pass < 3; ++pass) {
        #pragma unroll
        for (int j = 0; j < NC2; ++j) sp[j] = 0.0f;
        for (int c = grp; c < NC1; c += 64) {
            float p[8];
            #pragma unroll
            for (int k = 0; k < 8; ++k) p[k] = prim[c][k];
            const float* Wc = W + (size_t)c * (NC2 * ND2 * ND1) + d * ND1;
            float u[NC2];
            #pragma unroll
            for (int j = 0; j < NC2; ++j) {
                const float4 w0 = *(const float4*)(Wc + j * (ND2 * ND1));
                const float4 w1 = *(const float4*)(Wc + j * (ND2 * ND1) + 4);
                u[j] = w0.x*p[0] + w0.y*p[1] + w0.z*p[2] + w0.w*p[3]
                     + w1.x*p[4] + w1.y*p[5] + w1.z*p[6] + w1.w*p[7];
            }
            if (pass == 0) {
                #pragma unroll
                for (int j = 0; j < NC2; ++j) sp[j] += u[j];
            } else {
                float r[NC2];
                #pragma unroll
                for (int j = 0; j < NC2; ++j) {
                    float t = u[j] * vsum[j];
                    t += __shfl_xor(t, 1); t += __shfl_xor(t, 2);
                    t += __shfl_xor(t, 4); t += __shfl_xor(t, 8);
                    r[j] = t;
                }
                float m = r[0];
                #pragma unroll
                for (int j = 1; j < NC2; ++j) m = fmaxf(m, r[j]);
                float ssum = 0.0f;
                #pragma unroll
                for (int j = 0; j < NC2; ++j) { r[j] = __expf(r[j] - m); ssum += r[j]; }
                float inv = 1.0f / ssum;
                #pragma unroll
                for (int j = 0; j < NC2; ++j) sp[j] += (r[j] * inv) * u[j];
            }
        }
        #pragma unroll
        for (int j = 0; j < NC2; ++j) {
            sp[j] += __shfl_xor(sp[j], 16);
            sp[j] += __shfl_xor(sp[j], 32);
        }
        if (lane < 16) {
            #pragma unroll
            for (int j = 0; j < NC2; ++j) sred[wave][j * 16 + d] = sp[j];
        }
        __syncthreads();
        if (tid < SDIM) {
            float acc = 0.0f;
            #pragma unroll
            for (int w = 0; w < 16; ++w) acc += sred[w][tid];
            float s = bias[tid] + (pass == 0 ? 0.1f * acc : acc);
            float sq = s * s;
            sq += __shfl_xor(sq, 1); sq += __shfl_xor(sq, 2);
            sq += __shfl_xor(sq, 4); sq += __shfl_xor(sq, 8);
            float vv = (sq / (1.0f + sq)) * rsqrtf(sq + 1e-8f) * s;
            if (pass == 2) out[(size_t)b * SDIM + tid] = vv;
            else           vbuf[tid] = vv;
        }
        __syncthreads();
        if (pass < 2) {
            #pragma unroll
            for (int j = 0; j < NC2; ++j) {
                float vv = vbuf[j * 16 + d];
                vsum[j] = (pass == 0) ? vv : (vsum[j] + vv);
            }
        }
        __syncthreads();
    }
}

extern "C" void kernel_launch(void* const* d_in, const int* in_sizes, int n_in,
                              void* d_out, int out_size, void* d_ws, size_t ws_size,
                              hipStream_t stream) {
    const float* x    = (const float*)d_in[0];  // [128, 9216]
    const float* W    = (const float*)d_in[1];  // [1152, 10, 16, 8]
    const float* bias = (const float*)d_in[2];  // [1, 1, 10, 16]
    float* out = (float*)d_out;                 // [128, 1, 10, 16, 1]

    const size_t u_bytes  = (size_t)BATCH * 5 * NC1 * 16 * 4;  // 47,185,920
    const size_t s0_bytes = (size_t)BATCH * SDIM * 4;          // 81,920
    const size_t v_bytes  = (size_t)BATCH * SDIM * 4;          // 81,920
    const size_t sp_bytes = (size_t)BATCH * 4 * SDIM * 4;      // 327,680
    const size_t need = u_bytes + s0_bytes + v_bytes + sp_bytes;

    if (ws_size >= need) {
        unsigned* u_ws  = (unsigned*)d_ws;
        float*    s0    = (float*)((char*)d_ws + u_bytes);
        float*    v     = (float*)((char*)d_ws + u_bytes + s0_bytes);
        float*    spart = (float*)((char*)d_ws + u_bytes + s0_bytes + v_bytes);

        caps_zero <<<80, 256, 0, stream>>>(s0);
        caps_uhat <<<dim3(NC1 / CB, BATCH / BB), 512, 0, stream>>>(x, W, u_ws, s0);
        caps_pass <<<BATCH * 4, 512, 0, stream>>>(u_ws, s0, bias, spart, 0);
        caps_comb1<<<BATCH, 192, 0, stream>>>(s0, spart, bias, v);
        caps_pass <<<BATCH * 4, 512, 0, stream>>>(u_ws, v, bias, spart, 1);
        caps_comb2<<<BATCH, 192, 0, stream>>>(spart, bias, out);
    } else {
        caps_fused<<<BATCH, 1024, 0, stream>>>(x, W, bias, out);
    }
}

// Round 16
// 69.834 us; speedup vs baseline: 1.1547x; 1.1547x over previous
//
#include <hip/hip_runtime.h>
#include <hip/hip_fp16.h>

#define BATCH 128
#define NC1   1152
#define ND1   8
#define NC2   10
#define ND2   16
#define SDIM  (NC2 * ND2)    // 160

// kernel B tiling
#define CB 16                // caps per block
#define BB 32                // batch per block

__device__ __forceinline__ unsigned pack_h2(float a, float b) {
    __half2 h = __floats2half2_rn(a, b);
    return *reinterpret_cast<unsigned*>(&h);
}
__device__ __forceinline__ float2 unpack_h2(unsigned v) {
    __half2 h = *reinterpret_cast<__half2*>(&v);
    return __half22float2(h);
}
__device__ __forceinline__ unsigned pmul_h2(unsigned a, unsigned b) {
    __half2 ha = *reinterpret_cast<__half2*>(&a);
    __half2 hb = *reinterpret_cast<__half2*>(&b);
    __half2 r = __hmul2(ha, hb);
    return *reinterpret_cast<unsigned*>(&r);
}
__device__ __forceinline__ unsigned padd_h2(unsigned a, unsigned b) {
    __half2 ha = *reinterpret_cast<__half2*>(&a);
    __half2 hb = *reinterpret_cast<__half2*>(&b);
    __half2 r = __hadd2(ha, hb);
    return *reinterpret_cast<unsigned*>(&r);
}

// DPP row-rotate (within 16-lane row) on the VALU pipe -- replaces
// __shfl_xor (DS pipe) for the 16-lane agreement reduction.
// row_ror:N ctrl = 0x120 + N.
template<int CTRL>
__device__ __forceinline__ unsigned dpp_mov(unsigned v) {
    return (unsigned)__builtin_amdgcn_mov_dpp((int)v, CTRL, 0xF, 0xF, true);
}
__device__ __forceinline__ unsigned row_reduce_h2(unsigned t2) {
    t2 = padd_h2(t2, dpp_mov<0x128>(t2));   // ror 8
    t2 = padd_h2(t2, dpp_mov<0x124>(t2));   // ror 4
    t2 = padd_h2(t2, dpp_mov<0x122>(t2));   // ror 2
    t2 = padd_h2(t2, dpp_mov<0x121>(t2));   // ror 1
    return t2;                               // all 16 lanes hold the row sum
}

// ---- zero the s0 accumulator (atomics target) --------------------------
__global__ void caps_zero(float* __restrict__ s0) {
    s0[blockIdx.x * 256 + threadIdx.x] = 0.0f;   // grid 80 x 256 = 20480
}

// ---- Kernel B: u_hat (f16x2 -> ws) + fold pass-0 sum via atomics --------
// Thread (cl, d) keeps W[c,:,d,:] (80 f32) in regs, loops 32 batch elems.
// u_ws layout: uint f16x2 [b][jp][c][d]. Pass-0 s = 0.1*sum_c(u): packed-h2
// shfl over the wave's 4 caps (10 DS ops/b), 2 atomics per jp from lanes<16.
// (256,1) + single flat 80-reg W array is the ONLY shape the allocator
// keeps resident -- R10/R12/R14/R15 variations all regressed.
__global__ __launch_bounds__(256, 1) void caps_uhat(
    const float* __restrict__ x,     // [B, C1*D1]
    const float* __restrict__ W,     // [C1, C2, D2, D1]
    unsigned* __restrict__ u_ws,     // [B][5][C1][16]
    float* __restrict__ s0)          // [B][SDIM] (pre-zeroed)
{
    const int cb  = blockIdx.x;      // 0..71
    const int bb  = blockIdx.y;      // 0..3
    const int tid = threadIdx.x;
    const int cl  = tid >> 4;        // 0..15
    const int d   = tid & 15;
    const int wl  = tid & 63;        // lane in wave

    __shared__ float prim[BB][CB][ND1];  // 16 KB

    for (int i = tid; i < BB * CB; i += 256) {
        const int b = i >> 4, c = i & 15;
        const float* xr = x + ((size_t)(bb * BB + b) * NC1 + (cb * CB + c)) * ND1;
        float4 a0 = *(const float4*)(xr);
        float4 a1 = *(const float4*)(xr + 4);
        float sq = a0.x*a0.x + a0.y*a0.y + a0.z*a0.z + a0.w*a0.w
                 + a1.x*a1.x + a1.y*a1.y + a1.z*a1.z + a1.w*a1.w;
        float g = (sq / (1.0f + sq)) * rsqrtf(sq + 1e-8f);
        prim[b][c][0] = a0.x * g; prim[b][c][1] = a0.y * g;
        prim[b][c][2] = a0.z * g; prim[b][c][3] = a0.w * g;
        prim[b][c][4] = a1.x * g; prim[b][c][5] = a1.y * g;
        prim[b][c][6] = a1.z * g; prim[b][c][7] = a1.w * g;
    }
    __syncthreads();

    const int c_glob = cb * CB + cl;
    float w[NC2][ND1];
    #pragma unroll
    for (int j = 0; j < NC2; ++j) {
        const float* Wr = W + (((size_t)c_glob * NC2 + j) * ND2 + d) * ND1;
        float4 w0 = *(const float4*)(Wr);
        float4 w1 = *(const float4*)(Wr + 4);
        w[j][0] = w0.x; w[j][1] = w0.y; w[j][2] = w0.z; w[j][3] = w0.w;
        w[j][4] = w1.x; w[j][5] = w1.y; w[j][6] = w1.z; w[j][7] = w1.w;
    }

    for (int k = 0; k < BB; ++k) {
        const int b = (k + cb) & (BB - 1);   // stagger b order across c-blocks
        const int bglob = bb * BB + b;
        float p[ND1];
        #pragma unroll
        for (int kk = 0; kk < ND1; ++kk) p[kk] = prim[b][cl][kk];

        unsigned* ur = u_ws + ((size_t)bglob * 5 * NC1 + c_glob) * 16 + d;
        #pragma unroll
        for (int jp = 0; jp < 5; ++jp) {
            float u0 = 0.f, u1 = 0.f;
            #pragma unroll
            for (int kk = 0; kk < ND1; ++kk) {
                u0 += w[2*jp  ][kk] * p[kk];
                u1 += w[2*jp+1][kk] * p[kk];
            }
            unsigned pk = pack_h2(u0, u1);
            ur[(size_t)jp * (NC1 * 16)] = pk;
            // pass-0 partial: packed shfl over the wave's 4 caps (xor16,32)
            pk = padd_h2(pk, (unsigned)__shfl_xor((int)pk, 16));
            pk = padd_h2(pk, (unsigned)__shfl_xor((int)pk, 32));
            if (wl < 16) {
                float2 f = unpack_h2(pk);
                atomicAdd(&s0[(size_t)bglob * SDIM + (2*jp)   * 16 + d], f.x);
                atomicAdd(&s0[(size_t)bglob * SDIM + (2*jp+1) * 16 + d], f.y);
            }
        }
    }
}

// ---- one routing pass: partial s per (b, quarter) ------------------------
// Grid 512 = (b, q) x 512 thr = 32 groups x 16 lanes; 9 caps/group.
// mode 0: v_in = squash(0.1*s0 + bias) computed in-block.
// mode 1: v_in read directly from v buffer.
// Agreement dot: packed __half2 with DPP row_ror reduction -> VALU pipe,
// zero DS traffic in the hot loop.
__global__ __launch_bounds__(512, 1) void caps_pass(
    const unsigned* __restrict__ u_ws,  // [B][5][C1][16] f16x2
    const float* __restrict__ sv,       // mode0: s0 [B][SDIM]; mode1: v [B][SDIM]
    const float* __restrict__ bias,     // [SDIM]
    float* __restrict__ spart,          // [B][4][SDIM]
    int mode)
{
    const int bx   = blockIdx.x;
    const int b    = bx >> 2;
    const int q    = bx & 3;
    const int tid  = threadIdx.x;
    const int grp  = tid >> 4;   // 0..31
    const int d    = tid & 15;
    const int wave = tid >> 6;   // 0..7

    __shared__ float vl[SDIM];
    __shared__ float sred[8][SDIM];

    if (tid < SDIM) {
        float s = sv[(size_t)b * SDIM + tid];
        if (mode == 0) {
            s = 0.1f * s + bias[tid];
            float sq = s * s;
            sq += __shfl_xor(sq, 1); sq += __shfl_xor(sq, 2);
            sq += __shfl_xor(sq, 4); sq += __shfl_xor(sq, 8);
            s = (sq / (1.0f + sq)) * rsqrtf(sq + 1e-8f) * s;
        }
        vl[tid] = s;
    }
    __syncthreads();

    unsigned vsf[5];
    #pragma unroll
    for (int jp = 0; jp < 5; ++jp)
        vsf[jp] = pack_h2(vl[(2*jp)*16 + d], vl[(2*jp+1)*16 + d]);

    const unsigned* ub = u_ws + (size_t)b * 5 * NC1 * 16 + d;
    const int c0 = q * 288 + grp;       // caps c0 + i*32, i < 9

    float sp[NC2];
    #pragma unroll
    for (int j = 0; j < NC2; ++j) sp[j] = 0.0f;

    unsigned o[5], on[5];
    #pragma unroll
    for (int jp = 0; jp < 5; ++jp)
        o[jp] = ub[(size_t)jp * (NC1 * 16) + (size_t)c0 * 16];

    for (int i = 0; i < 9; ++i) {
        if (i + 1 < 9) {
            const int c = c0 + (i + 1) * 32;
            #pragma unroll
            for (int jp = 0; jp < 5; ++jp)
                on[jp] = ub[(size_t)jp * (NC1 * 16) + (size_t)c * 16];
        }
        float u[NC2], r[NC2];
        #pragma unroll
        for (int jp = 0; jp < 5; ++jp) {
            float2 f = unpack_h2(o[jp]);
            u[2*jp] = f.x; u[2*jp+1] = f.y;
            unsigned t2 = row_reduce_h2(pmul_h2(o[jp], vsf[jp]));  // VALU-only
            float2 rr = unpack_h2(t2);
            r[2*jp] = rr.x; r[2*jp+1] = rr.y;
        }
        float ssum = 0.0f;
        #pragma unroll
        for (int j = 0; j < NC2; ++j) { r[j] = __expf(r[j]); ssum += r[j]; }
        float inv = 1.0f / ssum;
        #pragma unroll
        for (int j = 0; j < NC2; ++j) sp[j] += (r[j] * inv) * u[j];
        #pragma unroll
        for (int jp = 0; jp < 5; ++jp) o[jp] = on[jp];
    }

    #pragma unroll
    for (int j = 0; j < NC2; ++j) {
        sp[j] += __shfl_xor(sp[j], 16);
        sp[j] += __shfl_xor(sp[j], 32);
    }
    if ((tid & 63) < 16) {
        #pragma unroll
        for (int j = 0; j < NC2; ++j) sred[wave][j * 16 + d] = sp[j];
    }
    __syncthreads();
    if (tid < SDIM) {
        float acc = 0.0f;
        #pragma unroll
        for (int w = 0; w < 8; ++w) acc += sred[w][tid];
        spart[((size_t)b * 4 + q) * SDIM + tid] = acc;
    }
}

// ---- combine: v = squash(0.1*s0+bias) + squash(sum spart + bias) ---------
__global__ void caps_comb1(const float* __restrict__ s0,
                           const float* __restrict__ spart,
                           const float* __restrict__ bias,
                           float* __restrict__ v) {   // grid 128 x 192
    const int b = blockIdx.x, tid = threadIdx.x;
    if (tid >= SDIM) return;
    float bv = bias[tid];
    float s_a = 0.1f * s0[(size_t)b * SDIM + tid] + bv;
    float s_b = spart[((size_t)b * 4 + 0) * SDIM + tid]
              + spart[((size_t)b * 4 + 1) * SDIM + tid]
              + spart[((size_t)b * 4 + 2) * SDIM + tid]
              + spart[((size_t)b * 4 + 3) * SDIM + tid] + bv;
    float qa = s_a * s_a;
    qa += __shfl_xor(qa, 1); qa += __shfl_xor(qa, 2);
    qa += __shfl_xor(qa, 4); qa += __shfl_xor(qa, 8);
    float qb = s_b * s_b;
    qb += __shfl_xor(qb, 1); qb += __shfl_xor(qb, 2);
    qb += __shfl_xor(qb, 4); qb += __shfl_xor(qb, 8);
    float v0 = (qa / (1.0f + qa)) * rsqrtf(qa + 1e-8f) * s_a;
    float v1 = (qb / (1.0f + qb)) * rsqrtf(qb + 1e-8f) * s_b;
    v[(size_t)b * SDIM + tid] = v0 + v1;
}

// ---- combine quarters -> out = squash(s)  (final) ------------------------
__global__ void caps_comb2(const float* __restrict__ spart,
                           const float* __restrict__ bias,
                           float* __restrict__ out) { // grid 128 x 192
    const int b = blockIdx.x, tid = threadIdx.x;
    if (tid >= SDIM) return;
    float s = spart[((size_t)b * 4 + 0) * SDIM + tid]
            + spart[((size_t)b * 4 + 1) * SDIM + tid]
            + spart[((size_t)b * 4 + 2) * SDIM + tid]
            + spart[((size_t)b * 4 + 3) * SDIM + tid] + bias[tid];
    float sq = s * s;
    sq += __shfl_xor(sq, 1); sq += __shfl_xor(sq, 2);
    sq += __shfl_xor(sq, 4); sq += __shfl_xor(sq, 8);
    out[(size_t)b * SDIM + tid] = (sq / (1.0f + sq)) * rsqrtf(sq + 1e-8f) * s;
}

// ---- Fallback: round-1 fused kernel (proven, 198 us) ---------------------
__global__ __launch_bounds__(1024) void caps_fused(
    const float* __restrict__ x, const float* __restrict__ W,
    const float* __restrict__ bias, float* __restrict__ out)
{
    const int b    = blockIdx.x;
    const int tid  = threadIdx.x;
    const int grp  = tid >> 4;
    const int d    = tid & 15;
    const int wave = tid >> 6;
    const int lane = tid & 63;

    __shared__ float prim[NC1][ND1];
    __shared__ float sred[16][SDIM];
    __shared__ float vbuf[SDIM];

    const float* xb = x + (size_t)b * (NC1 * ND1);
    for (int c = tid; c < NC1; c += 1024) {
        float4 a0 = *(const float4*)(xb + c * 8);
        float4 a1 = *(const float4*)(xb + c * 8 + 4);
        float sq = a0.x*a0.x + a0.y*a0.y + a0.z*a0.z + a0.w*a0.w
                 + a1.x*a1.x + a1.y*a1.y + a1.z*a1.z + a1.w*a1.w;
        float g = (sq / (1.0f + sq)) * rsqrtf(sq + 1e-8f);
        prim[c][0] = a0.x * g; prim[c][1] = a0.y * g;
        prim[c][2] = a0.z * g; prim[c][3] = a0.w * g;
        prim[c][4] = a1.x * g; prim[c][5] = a1.y * g;
        prim[c][6] = a1.z * g; prim[c][7] = a1.w * g;
    }
    __syncthreads();

    float vsum[NC2], sp[NC2];
    for (int pass = 0; pass < 3; ++pass) {
        #pragma unroll
        for (int j = 0; j < NC2; ++j) sp[j] = 0.0f;
        for (int c = grp; c < NC1; c += 64) {
            float p[8];
            #pragma unroll
            for (int k = 0; k < 8; ++k) p[k] = prim[c][k];
            const float* Wc = W + (size_t)c * (NC2 * ND2 * ND1) + d * ND1;
            float u[NC2];
            #pragma unroll
            for (int j = 0; j < NC2; ++j) {
                const float4 w0 = *(const float4*)(Wc + j * (ND2 * ND1));
                const float4 w1 = *(const float4*)(Wc + j * (ND2 * ND1) + 4);
                u[j] = w0.x*p[0] + w0.y*p[1] + w0.z*p[2] + w0.w*p[3]
                     + w1.x*p[4] + w1.y*p[5] + w1.z*p[6] + w1.w*p[7];
            }
            if (pass == 0) {
                #pragma unroll
                for (int j = 0; j < NC2; ++j) sp[j] += u[j];
            } else {
                float r[NC2];
                #pragma unroll
                for (int j = 0; j < NC2; ++j) {
                    float t = u[j] * vsum[j];
                    t += __shfl_xor(t, 1); t += __shfl_xor(t, 2);
                    t += __shfl_xor(t, 4); t += __shfl_xor(t, 8);
                    r[j] = t;
                }
                float m = r[0];
                #pragma unroll
                for (int j = 1; j < NC2; ++j) m = fmaxf(m, r[j]);
                float ssum = 0.0f;
                #pragma unroll
                for (int j = 0; j < NC2; ++j) { r[j] = __expf(r[j] - m); ssum += r[j]; }
                float inv = 1.0f / ssum;
                #pragma unroll
                for (int j = 0; j < NC2; ++j) sp[j] += (r[j] * inv) * u[j];
            }
        }
        #pragma unroll
        for (int j = 0; j < NC2; ++j) {
            sp[j] += __shfl_xor(sp[j], 16);
            sp[j] += __shfl_xor(sp[j], 32);
        }
        if (lane < 16) {
            #pragma unroll
            for (int j = 0; j < NC2; ++j) sred[wave][j * 16 + d] = sp[j];
        }
        __syncthreads();
        if (tid < SDIM) {
            float acc = 0.0f;
            #pragma unroll
            for (int w = 0; w < 16; ++w) acc += sred[w][tid];
            float s = bias[tid] + (pass == 0 ? 0.1f * acc : acc);
            float sq = s * s;
            sq += __shfl_xor(sq, 1); sq += __shfl_xor(sq, 2);
            sq += __shfl_xor(sq, 4); sq += __shfl_xor(sq, 8);
            float vv = (sq / (1.0f + sq)) * rsqrtf(sq + 1e-8f) * s;
            if (pass == 2) out[(size_t)b * SDIM + tid] = vv;
            else           vbuf[tid] = vv;
        }
        __syncthreads();
        if (pass < 2) {
            #pragma unroll
            for (int j = 0; j < NC2; ++j) {
                float vv = vbuf[j * 16 + d];
                vsum[j] = (pass == 0) ? vv : (vsum[j] + vv);
            }
        }
        __syncthreads();
    }
}

extern "C" void kernel_launch(void* const* d_in, const int* in_sizes, int n_in,
                              void* d_out, int out_size, void* d_ws, size_t ws_size,
                              hipStream_t stream) {
    const float* x    = (const float*)d_in[0];  // [128, 9216]
    const float* W    = (const float*)d_in[1];  // [1152, 10, 16, 8]
    const float* bias = (const float*)d_in[2];  // [1, 1, 10, 16]
    float* out = (float*)d_out;                 // [128, 1, 10, 16, 1]

    const size_t u_bytes  = (size_t)BATCH * 5 * NC1 * 16 * 4;  // 47,185,920
    const size_t s0_bytes = (size_t)BATCH * SDIM * 4;          // 81,920
    const size_t v_bytes  = (size_t)BATCH * SDIM * 4;          // 81,920
    const size_t sp_bytes = (size_t)BATCH * 4 * SDIM * 4;      // 327,680
    const size_t need = u_bytes + s0_bytes + v_bytes + sp_bytes; // 47,677,440

    if (ws_size >= need) {
        unsigned* u_ws  = (unsigned*)d_ws;
        float*    s0    = (float*)((char*)d_ws + u_bytes);
        float*    v     = (float*)((char*)d_ws + u_bytes + s0_bytes);
        float*    spart = (float*)((char*)d_ws + u_bytes + s0_bytes + v_bytes);

        caps_zero <<<80, 256, 0, stream>>>(s0);
        caps_uhat <<<dim3(NC1 / CB, BATCH / BB), 256, 0, stream>>>(x, W, u_ws, s0);
        caps_pass <<<BATCH * 4, 512, 0, stream>>>(u_ws, s0, bias, spart, 0);
        caps_comb1<<<BATCH, 192, 0, stream>>>(s0, spart, bias, v);
        caps_pass <<<BATCH * 4, 512, 0, stream>>>(u_ws, v, bias, spart, 1);
        caps_comb2<<<BATCH, 192, 0, stream>>>(spart, bias, out);
    } else {
        caps_fused<<<BATCH, 1024, 0, stream>>>(x, W, bias, out);
    }
}